// Round 1
// 254.110 us; speedup vs baseline: 1.3180x; 1.3180x over previous
//
#include <hip/hip_runtime.h>

// Round 4: single fused kernel.
//   prep_weights: pack W1/W2/W3 into bf16 A-operand fragments (transposed MLP).
//   fused_kernel: rolling-window Sobel -> bf16 feats in LDS (wave-private) ->
//                 48->128->128->16 MFMA chain -> LDS transpose -> full-line stores.
// Removes the 192 MB feats HBM round-trip and the partial-line write amplification
// (was 157 MB written vs 64 ideal). Two barriers per row; next-row x loads issued
// before Sobel so HBM latency hides under compute.

#define NPX (1u << 20)

using bf16x8 = __attribute__((ext_vector_type(8))) __bf16;
using f32x4  = __attribute__((ext_vector_type(4))) float;

__device__ __forceinline__ unsigned f2bf(float f) {
    unsigned u = __float_as_uint(f);
    u += 0x7fffu + ((u >> 16) & 1u);   // RNE; inputs finite
    return u >> 16;
}

// ---- ws layout (ushort offsets): weight frags only ----
#define WS1_OFF 0        // [mt=8][kb=2][lane=64][8]  A-frags of W1^T (K-pad 48->64)
#define WS2_OFF 8192     // [mt=8][kb=4][lane=64][8]  A-frags of W2^T
#define WS3_OFF 24576    // [kb=4][lane=64][8]        A-frags of W3^T

__global__ __launch_bounds__(1024)
void prep_weights(const float* __restrict__ w1, const float* __restrict__ w2,
                  const float* __restrict__ w3, unsigned short* __restrict__ ws) {
    const int s = threadIdx.x;           // 1024 threads, 1 block
    {   // ws1: 1024 slots  (feature order k = 3*c + t; w1 row = t*16 + c)
        const int mt = s >> 7, kb = (s >> 6) & 1, lane = s & 63;
        const int q = lane >> 4, ln = lane & 15;
#pragma unroll
        for (int j = 0; j < 8; ++j) {
            const int k = kb * 32 + q * 8 + j;
            float val = 0.f;
            if (k < 48) { const int c = k / 3, t = k - 3 * c; val = w1[(t * 16 + c) * 128 + mt * 16 + ln]; }
            ws[WS1_OFF + s * 8 + j] = (unsigned short)f2bf(val);
        }
    }
    for (int s2 = s; s2 < 2048; s2 += 1024) {   // ws2: 2048 slots
        const int mt = s2 >> 8, kb = (s2 >> 6) & 3, lane = s2 & 63;
        const int q = lane >> 4, ln = lane & 15;
#pragma unroll
        for (int j = 0; j < 8; ++j) {
            const int k = kb * 32 + q * 8 + j;
            ws[WS2_OFF + s2 * 8 + j] = (unsigned short)f2bf(w2[k * 128 + mt * 16 + ln]);
        }
    }
    if (s < 256) {   // ws3: 256 slots
        const int kb = s >> 6, lane = s & 63;
        const int q = lane >> 4, ln = lane & 15;
#pragma unroll
        for (int j = 0; j < 8; ++j) {
            const int k = kb * 32 + q * 8 + j;
            ws[WS3_OFF + s * 8 + j] = (unsigned short)f2bf(w3[k * 16 + ln]);
        }
    }
}

// ===================== fused kernel =====================
// 512 blocks = 16 batches x 32 strips of 8 rows; 256 threads = 4 waves.
// Thread t = column t for Sobel, so wave w produces featsL/selL for exactly the
// 64-px tile wave w consumes in the MFMA phase (wave-private, no barrier needed).
#define XS_W 260   // 256 cols + pad; row start stays 16B aligned (260*4 % 16 == 0)

// LDS layout (bytes), total 161792 <= 163840:
#define SM_XS     0        // float xs[3][16][260]            = 49920
#define SM_FEATS  49920    // ushort featsL[256][56] (112B/px) = 28672 (2-way banks)
#define SM_SEL    78592    // float selL[256]                 = 1024
#define SM_W2     79616    // W2 A-frags                       = 32768
#define SM_H      112384   // per wave: Ha 4096 + Hb 4096      = 32768
#define SM_OBUF   145152   // per wave: float[16][65]          = 16640
#define SM_TOTAL  161792

#define H_SWZ(j, ln) ((((j) ^ ((ln) & 7)) << 4))

extern "C" __global__ __launch_bounds__(256, 1)
void fused_kernel(const float* __restrict__ x, const float* __restrict__ fmask,
                  const unsigned short* __restrict__ wf,
                  const float* __restrict__ b1, const float* __restrict__ b2,
                  const float* __restrict__ b3, float* __restrict__ out) {
    extern __shared__ char smem[];
    float (*xs)[16][XS_W] = (float (*)[16][XS_W])(smem + SM_XS);
    unsigned short* featsL = (unsigned short*)(smem + SM_FEATS);
    float* selL = (float*)(smem + SM_SEL);
    char* W2L = smem + SM_W2;

    const int t = threadIdx.x;
    const int wv = t >> 6, lane = t & 63;
    const int q = lane >> 4, ln = lane & 15;
    char* Ha = smem + SM_H + wv * 8192;
    char* Hb = Ha + 4096;
    float* OB = (float*)(smem + SM_OBUF + wv * 4160);

    const int bb = blockIdx.x >> 5;
    const int h0 = (blockIdx.x & 31) << 3;
    const float* xb = x + ((size_t)bb << 20);

    // ---- stage W2 frags -> LDS (block-shared, coalesced) ----
    {
        const uint4* src = (const uint4*)(wf + WS2_OFF);
        uint4* dst = (uint4*)W2L;
#pragma unroll
        for (int i = 0; i < 8; ++i) dst[t + i * 256] = src[t + i * 256];
    }
    // ---- W1/W3 frags -> VGPRs (80 regs, resident) ----
    bf16x8 W1f[8][2], W3f[4];
#pragma unroll
    for (int mt = 0; mt < 8; ++mt) {
        W1f[mt][0] = *(const bf16x8*)(wf + WS1_OFF + ((mt * 2 + 0) * 64 + lane) * 8);
        W1f[mt][1] = *(const bf16x8*)(wf + WS1_OFF + ((mt * 2 + 1) * 64 + lane) * 8);
    }
#pragma unroll
    for (int kb = 0; kb < 4; ++kb)
        W3f[kb] = *(const bf16x8*)(wf + WS3_OFF + (kb * 64 + lane) * 8);

    // ---- Sobel column constants ----
    const int col = t;
    const int cL = (col > 0)   ? col - 1 : 0;
    const int cR = (col < 255) ? col + 1 : 255;
    const float mL = (col > 0)   ? 1.f : 0.f;
    const float mR = (col < 255) ? 1.f : 0.f;

    float4 stg[4];
#define STAGE_ISSUE(r2) do { _Pragma("unroll")                                   \
    for (int i = 0; i < 4; ++i) {                                                \
        const int idx = t + i * 256;                                             \
        const int ch = idx >> 6; const int c4 = (idx & 63) << 2;                 \
        float4 v = make_float4(0.f, 0.f, 0.f, 0.f);                              \
        if ((unsigned)(r2) < 256u)                                               \
            v = *(const float4*)(xb + ((size_t)ch << 16) + (r2) * 256 + c4);     \
        stg[i] = v; } } while (0)
#define STAGE_STORE(slot) do { _Pragma("unroll")                                 \
    for (int i = 0; i < 4; ++i) {                                                \
        const int idx = t + i * 256;                                             \
        const int ch = idx >> 6; const int c4 = (idx & 63) << 2;                 \
        *(float4*)&xs[slot][ch][c4] = stg[i]; } } while (0)

    // prologue: rows h0-1, h0 into slots; row h0+1 in flight
    STAGE_ISSUE(h0 - 1); STAGE_STORE((h0 + 2) % 3);
    STAGE_ISSUE(h0);     STAGE_STORE(h0 % 3);
    STAGE_ISSUE(h0 + 1);

    for (int rr = 0; rr < 8; ++rr) {
        const int r = h0 + rr;
        STAGE_STORE((r + 1) % 3);        // vmcnt-waits on in-flight row r+1
        __syncthreads();                 // xs slots r-1, r, r+1 valid for everyone
        if (rr < 7) STAGE_ISSUE(r + 2);  // next row's loads fly under Sobel+MFMA
        const float fv = fmask[((size_t)bb << 16) + r * 256 + col];

        // ---- Sobel + pack (thread = column; wave-private featsL/selL region) ----
        const int sT = (r + 2) % 3, sC = r % 3, sB = (r + 1) % 3;
        unsigned pk[24];
        unsigned carry = 0;
        float selv = 0.f;
#pragma unroll
        for (int c = 0; c < 16; ++c) {
            const float* rT = xs[sT][c];
            const float* rC = xs[sC][c];
            const float* rB = xs[sB][c];
            const float v00 = rT[cL] * mL, v01 = rT[col], v02 = rT[cR] * mR;
            const float v10 = rC[cL] * mL, v11 = rC[col], v12 = rC[cR] * mR;
            const float v20 = rB[cL] * mL, v21 = rB[col], v22 = rB[cR] * mR;
            const float sx = (v02 + 2.f * v12 + v22) - (v00 + 2.f * v10 + v20);
            const float sy = (v20 + 2.f * v21 + v22) - (v00 + 2.f * v01 + v02);
            if (c == 3) {   // exact fp32 3x3 maxpool of alpha (x >= 0 -> zero-pad safe)
                float mx = fmaxf(fmaxf(fmaxf(v00, v01), fmaxf(v02, v10)),
                                 fmaxf(fmaxf(v11, v12), fmaxf(fmaxf(v20, v21), v22)));
                selv = (mx > 0.1f) ? 1.f : 0.f;
            }
            const unsigned ux = f2bf(v11), usx = f2bf(sx), usy = f2bf(sy);
            if ((c & 1) == 0) { pk[(c >> 1) * 3] = ux | (usx << 16); carry = usy; }
            else { pk[(c >> 1) * 3 + 1] = carry | (ux << 16);
                   pk[(c >> 1) * 3 + 2] = usx | (usy << 16); }
        }
        selL[col] = (fv != 0.f) ? selv : 0.f;
        {
            uint4* dstf = (uint4*)(featsL + col * 56);
#pragma unroll
            for (int j = 0; j < 6; ++j)
                dstf[j] = make_uint4(pk[j * 4 + 0], pk[j * 4 + 1], pk[j * 4 + 2], pk[j * 4 + 3]);
        }
        __syncthreads();   // guards xs slot reuse next iter (featsL is wave-private)

        // ---- MLP: wave tile = 64 px of this row; Ha/Hb alternate per sub ----
#pragma unroll
        for (int sub = 0; sub < 4; ++sub) {
            char* H = (sub & 1) ? Hb : Ha;
            const int pxl = wv * 64 + sub * 16 + ln;   // this lane's pixel (B-frag col)
            const unsigned short* fp = featsL + pxl * 56;
            const bf16x8 Bk0 = *(const bf16x8*)(fp + q * 8);         // k = q*8..+7
            bf16x8 Bk1 = {};
            if (q < 2) Bk1 = *(const bf16x8*)(fp + 32 + q * 8);      // k = 32..47
            // ---- layer 1: H^T = relu(W1^T F^T + b1) ----
#pragma unroll
            for (int mt = 0; mt < 8; ++mt) {
                f32x4 acc = *(const f32x4*)(b1 + mt * 16 + q * 4);
                acc = __builtin_amdgcn_mfma_f32_16x16x32_bf16(W1f[mt][0], Bk0, acc, 0, 0, 0);
                acc = __builtin_amdgcn_mfma_f32_16x16x32_bf16(W1f[mt][1], Bk1, acc, 0, 0, 0);
                const unsigned r01 = f2bf(fmaxf(acc[0], 0.f)) | (f2bf(fmaxf(acc[1], 0.f)) << 16);
                const unsigned r23 = f2bf(fmaxf(acc[2], 0.f)) | (f2bf(fmaxf(acc[3], 0.f)) << 16);
                *(uint2*)(H + ln * 256 + H_SWZ(mt * 2 + (q >> 1), ln) + ((q & 1) << 3))
                    = make_uint2(r01, r23);
            }
            bf16x8 B2[4];
#pragma unroll
            for (int kb = 0; kb < 4; ++kb)
                B2[kb] = *(const bf16x8*)(H + ln * 256 + H_SWZ(kb * 4 + q, ln));
            // ---- layer 2 (overwrites H in place; B2 already in regs) ----
#pragma unroll
            for (int mt = 0; mt < 8; ++mt) {
                f32x4 acc = *(const f32x4*)(b2 + mt * 16 + q * 4);
#pragma unroll
                for (int kb = 0; kb < 4; ++kb) {
                    const bf16x8 Af = *(const bf16x8*)(W2L + ((mt * 4 + kb) * 64 + lane) * 16);
                    acc = __builtin_amdgcn_mfma_f32_16x16x32_bf16(Af, B2[kb], acc, 0, 0, 0);
                }
                const unsigned r01 = f2bf(fmaxf(acc[0], 0.f)) | (f2bf(fmaxf(acc[1], 0.f)) << 16);
                const unsigned r23 = f2bf(fmaxf(acc[2], 0.f)) | (f2bf(fmaxf(acc[3], 0.f)) << 16);
                *(uint2*)(H + ln * 256 + H_SWZ(mt * 2 + (q >> 1), ln) + ((q & 1) << 3))
                    = make_uint2(r01, r23);
            }
            // ---- layer 3: U^T = W3^T H^T + b3 ----
            f32x4 acc3 = *(const f32x4*)(b3 + q * 4);
#pragma unroll
            for (int kb = 0; kb < 4; ++kb) {
                const bf16x8 B3 = *(const bf16x8*)(H + ln * 256 + H_SWZ(kb * 4 + q, ln));
                acc3 = __builtin_amdgcn_mfma_f32_16x16x32_bf16(W3f[kb], B3, acc3, 0, 0, 0);
            }
            // ---- mask + stage into OBUF (ch-major, 65-float stride: no conflicts) ----
            const float sv = selL[pxl];
#pragma unroll
            for (int r4 = 0; r4 < 4; ++r4)
                OB[(q * 4 + r4) * 65 + sub * 16 + ln] = acc3[r4] * sv;
        }
        // ---- store: per channel, 64 lanes x 4B = full aligned 256B line ----
        {
            float* orow = out + (((size_t)bb * 16) << 16) + (size_t)r * 256 + wv * 64 + lane;
#pragma unroll
            for (int ch = 0; ch < 16; ++ch)
                orow[(size_t)ch << 16] = OB[ch * 65 + lane];
        }
    }
#undef STAGE_ISSUE
#undef STAGE_STORE
}

extern "C" void kernel_launch(void* const* d_in, const int* in_sizes, int n_in,
                              void* d_out, int out_size, void* d_ws, size_t ws_size,
                              hipStream_t stream) {
    (void)in_sizes; (void)n_in; (void)out_size; (void)ws_size;
    const float* x  = (const float*)d_in[0];
    const float* fm = (const float*)d_in[1];
    const float* w1 = (const float*)d_in[2];
    const float* b1 = (const float*)d_in[3];
    const float* w2 = (const float*)d_in[4];
    const float* b2 = (const float*)d_in[5];
    const float* w3 = (const float*)d_in[6];
    const float* b3 = (const float*)d_in[7];
    float* o = (float*)d_out;
    unsigned short* ws = (unsigned short*)d_ws;

    prep_weights<<<dim3(1), dim3(1024), 0, stream>>>(w1, w2, w3, ws);

    hipFuncSetAttribute((const void*)fused_kernel,
                        hipFuncAttributeMaxDynamicSharedMemorySize, SM_TOTAL);
    fused_kernel<<<dim3(512), dim3(256), SM_TOTAL, stream>>>(x, fm, ws, b1, b2, b3, o);
}